// Round 12
// baseline (197.190 us; speedup 1.0000x reference)
//
#include <hip/hip_runtime.h>

#define BATCH 2
#define SEQL  2048
#define NEMB  1024
#define NH    16
#define HD    64
#define MROWS (BATCH*SEQL)   // 4096

// Q prescale: sqrt(C) * log2(e) so scores are in exp2 domain
#define QSCALE 46.166241308446828f

typedef short bf16x8 __attribute__((ext_vector_type(8)));
typedef float f32x16 __attribute__((ext_vector_type(16)));

// round-to-nearest-even float -> bf16 bits
__device__ __forceinline__ unsigned short f2bf(float x) {
    union { float f; unsigned u; } v; v.f = x;
    unsigned r = v.u + 0x7FFFu + ((v.u >> 16) & 1u);
    return (unsigned short)(r >> 16);
}
__device__ __forceinline__ void split_bf16(float x, unsigned short& hi, unsigned short& lo) {
    hi = f2bf(x);
    union { unsigned u; float f; } h; h.u = ((unsigned)hi) << 16;
    lo = f2bf(x - h.f);
}
__device__ __forceinline__ float bf2f(unsigned short b) {
    union { unsigned u; float f; } v; v.u = ((unsigned)b) << 16;
    return v.f;
}
// packed f32x2 -> bf16x2 (hardware cvt, RNE)
__device__ __forceinline__ unsigned cvt_pk_bf16(float a, float b) {
    unsigned r;
    asm("v_cvt_pk_bf16_f32 %0, %1, %2" : "=v"(r) : "v"(a), "v"(b));
    return r;
}
// v_permlane32_swap_b32: a.hi_lanes <-> b.lo_lanes (full-rate VALU lane swap)
__device__ __forceinline__ void plane_swap(unsigned& a, unsigned& b) {
    asm volatile("v_permlane32_swap_b32 %0, %1" : "+v"(a), "+v"(b));
}

// Padded fragment-linear LDS slot (16B units): chunk stride 66, half offset 33.
__device__ __forceinline__ int slot16(int chunk, int lane) {
    return chunk * 66 + (lane & 31) + 33 * (lane >> 5);
}

// ---------------------------------------------------------------------------
// Pass 1: ix (fp32) -> ix_hi, ix_lo (bf16), row-major [m][c].
// ---------------------------------------------------------------------------
__global__ __launch_bounds__(256) void split_convert_kernel(
    const float* __restrict__ src,
    unsigned short* __restrict__ dhi, unsigned short* __restrict__ dlo)
{
    int i = (blockIdx.x * 256 + threadIdx.x) * 4;
    float4 v = *(const float4*)(src + i);
    unsigned short h[4], l[4];
    split_bf16(v.x, h[0], l[0]); split_bf16(v.y, h[1], l[1]);
    split_bf16(v.z, h[2], l[2]); split_bf16(v.w, h[3], l[3]);
    uint2 ph, pl;
    ph.x = h[0] | ((unsigned)h[1] << 16); ph.y = h[2] | ((unsigned)h[3] << 16);
    pl.x = l[0] | ((unsigned)l[1] << 16); pl.y = l[2] | ((unsigned)l[3] << 16);
    *(uint2*)(dhi + i) = ph;
    *(uint2*)(dlo + i) = pl;
}

// ---------------------------------------------------------------------------
// Pass 2: transpose + convert weights -> Wt[n][c] (k-fast) bf16.
// ---------------------------------------------------------------------------
__global__ __launch_bounds__(256) void transpose_convert_kernel(
    const float* __restrict__ Wq, const float* __restrict__ Wk,
    const float* __restrict__ Wv, const float* __restrict__ Wp,
    unsigned short* __restrict__ qhi, unsigned short* __restrict__ qlo,
    unsigned short* __restrict__ khi, unsigned short* __restrict__ klo,
    unsigned short* __restrict__ vhi, unsigned short* __restrict__ pt)
{
    __shared__ float tile[64][68];
    const int z = blockIdx.z, hb = blockIdx.y, c0 = blockIdx.x * 64;
    const float* src; int rstride; unsigned short* dhi; unsigned short* dlo;
    if (z == 0)      { src = Wq + (size_t)hb * 65536; rstride = 64;   dhi = qhi; dlo = qlo; }
    else if (z == 1) { src = Wk + (size_t)hb * 65536; rstride = 64;   dhi = khi; dlo = klo; }
    else if (z == 2) { src = Wv + (size_t)hb * 65536; rstride = 64;   dhi = vhi; dlo = nullptr; }
    else             { src = Wp + (size_t)hb * 64;    rstride = 1024; dhi = pt;  dlo = nullptr; }
    const int tid = threadIdx.x;
    #pragma unroll
    for (int i = 0; i < 4; ++i) {
        int fidx = i * 256 + tid;
        int r  = fidx >> 4;
        int dq = (fidx & 15) * 4;
        float4 v = *(const float4*)(src + (size_t)(c0 + r) * rstride + dq);
        *(float4*)&tile[r][dq] = v;
    }
    __syncthreads();
    #pragma unroll
    for (int i = 0; i < 4; ++i) {
        int fidx = i * 256 + tid;
        int d  = fidx >> 4;
        int cq = (fidx & 15) * 4;
        size_t base = (size_t)(hb * 64 + d) * 1024 + c0 + cq;
        unsigned short hh[4], ll[4];
        #pragma unroll
        for (int j = 0; j < 4; ++j) split_bf16(tile[cq + j][d], hh[j], ll[j]);
        uint2 ph; ph.x = hh[0] | ((unsigned)hh[1] << 16); ph.y = hh[2] | ((unsigned)hh[3] << 16);
        *(uint2*)(dhi + base) = ph;
        if (dlo) {
            uint2 pl; pl.x = ll[0] | ((unsigned)ll[1] << 16); pl.y = ll[2] | ((unsigned)ll[3] << 16);
            *(uint2*)(dlo + base) = pl;
        }
    }
}

// ---------------------------------------------------------------------------
// Fused QKV projection GEMM, BM=BN=128, BK=32 (round-10 structure), with
// Z-INTERLEAVED 1D grid: bid -> (z = bid%3, xy = bid/3).  Consecutive bids
// are {Q,K,V} of the SAME tile (shared A-tile in L2), and mixed-duration
// blocks pack the 2/CU residency slots without a z-major tail.
// ---------------------------------------------------------------------------
__global__ __launch_bounds__(256, 2) void qkv_gemm(
    const unsigned short* __restrict__ Ahi, const unsigned short* __restrict__ Alo,
    const unsigned short* __restrict__ Bq_hi, const unsigned short* __restrict__ Bq_lo,
    const unsigned short* __restrict__ Bk_hi, const unsigned short* __restrict__ Bk_lo,
    const unsigned short* __restrict__ Bv_hi,
    unsigned short* __restrict__ Qhi, unsigned short* __restrict__ Qlo,
    unsigned short* __restrict__ Khi, unsigned short* __restrict__ Klo,
    unsigned short* __restrict__ Vt)
{
    __shared__ unsigned short smem[2][4][4224];   // [buf][Ahi,Bhi,Alo,Blo]

    const int bid = blockIdx.x;          // 0..767
    const int z   = bid % 3;
    const int xy  = bid / 3;             // 0..255
    const int m0  = (xy & 31) * 128;
    const int n0  = (xy >> 5) * 128;

    const bool split = (z < 2);
    const unsigned short* __restrict__ Bhi = (z == 0) ? Bq_hi : (z == 1) ? Bk_hi : Bv_hi;
    const unsigned short* __restrict__ Blo = (z == 0) ? Bq_lo : Bk_lo;
    unsigned short* __restrict__ Ohi = (z == 0) ? Qhi : Khi;
    unsigned short* __restrict__ Olo = (z == 0) ? Qlo : Klo;
    const float oscale = (z == 0) ? QSCALE : 1.0f;

    const int tid  = threadIdx.x;
    const int wid  = tid >> 6, lane = tid & 63;
    const int wr   = wid >> 1, wc = wid & 1;

    int roff_[2], slot_[2];
    #pragma unroll
    for (int q = 0; q < 2; ++q) {
        int f   = q * 256 + tid;
        int row = f >> 2;
        int k8  = (f & 3) * 8;
        roff_[q] = row * 1024 + k8;
        slot_[q] = slot16((row >> 5) * 2 + (k8 >> 4), (row & 31) + 32 * ((k8 >> 3) & 1)) * 8;
    }
    const unsigned short* __restrict__ Ah = Ahi + (size_t)m0 * 1024;
    const unsigned short* __restrict__ Bh = Bhi + (size_t)n0 * 1024;
    const unsigned short* __restrict__ Al = split ? Alo + (size_t)m0 * 1024 : Ahi;
    const unsigned short* __restrict__ Bl = split ? Blo + (size_t)n0 * 1024 : Bhi;

    bf16x8 pah[2], pbh[2], pal[2], pbl[2];

    #define LOADT(KK)  do { _Pragma("unroll")                                   \
        for (int q = 0; q < 2; ++q) {                                           \
            pah[q] = *(const bf16x8*)(Ah + roff_[q] + (KK));                    \
            pbh[q] = *(const bf16x8*)(Bh + roff_[q] + (KK));                    \
            if (split) {                                                        \
                pal[q] = *(const bf16x8*)(Al + roff_[q] + (KK));                \
                pbl[q] = *(const bf16x8*)(Bl + roff_[q] + (KK));                \
            }                                                                   \
        } } while (0)

    #define WRITET(NB) do { _Pragma("unroll")                                   \
        for (int q = 0; q < 2; ++q) {                                           \
            *(bf16x8*)(&smem[NB][0][slot_[q]]) = pah[q];                        \
            *(bf16x8*)(&smem[NB][1][slot_[q]]) = pbh[q];                        \
            if (split) {                                                        \
                *(bf16x8*)(&smem[NB][2][slot_[q]]) = pal[q];                    \
                *(bf16x8*)(&smem[NB][3][slot_[q]]) = pbl[q];                    \
            }                                                                   \
        } } while (0)

    f32x16 acc[2][2] = {};

    LOADT(0);
    WRITET(0);
    LOADT(32);

    for (int t = 0; t < 32; ++t) {
        __syncthreads();
        if (t + 1 < 32) {
            WRITET((t + 1) & 1);
            if (t + 2 < 32) LOADT((t + 2) * 32);
        }
        const int cb = t & 1;
        const unsigned short* a_hi = smem[cb][0];
        const unsigned short* b_hi = smem[cb][1];
        const unsigned short* a_lo = smem[cb][2];
        const unsigned short* b_lo = smem[cb][3];

        #pragma unroll
        for (int kch = 0; kch < 2; ++kch) {
            bf16x8 ah[2], bh_[2];
            #pragma unroll
            for (int mt = 0; mt < 2; ++mt)
                ah[mt] = *(const bf16x8*)(a_hi + slot16((2 * wr + mt) * 2 + kch, lane) * 8);
            #pragma unroll
            for (int nt = 0; nt < 2; ++nt)
                bh_[nt] = *(const bf16x8*)(b_hi + slot16((2 * wc + nt) * 2 + kch, lane) * 8);
            if (split) {
                bf16x8 al[2], bl[2];
                #pragma unroll
                for (int mt = 0; mt < 2; ++mt)
                    al[mt] = *(const bf16x8*)(a_lo + slot16((2 * wr + mt) * 2 + kch, lane) * 8);
                #pragma unroll
                for (int nt = 0; nt < 2; ++nt)
                    bl[nt] = *(const bf16x8*)(b_lo + slot16((2 * wc + nt) * 2 + kch, lane) * 8);
                #pragma unroll
                for (int mt = 0; mt < 2; ++mt)
                    #pragma unroll
                    for (int nt = 0; nt < 2; ++nt) {
                        acc[mt][nt] = __builtin_amdgcn_mfma_f32_32x32x16_bf16(ah[mt], bh_[nt], acc[mt][nt], 0, 0, 0);
                        acc[mt][nt] = __builtin_amdgcn_mfma_f32_32x32x16_bf16(ah[mt], bl[nt],  acc[mt][nt], 0, 0, 0);
                        acc[mt][nt] = __builtin_amdgcn_mfma_f32_32x32x16_bf16(al[mt], bh_[nt], acc[mt][nt], 0, 0, 0);
                    }
            } else {
                // z==2: swap operands -> acc = (W-tile) x (ix-tile) = V^T tile
                #pragma unroll
                for (int mt = 0; mt < 2; ++mt)
                    #pragma unroll
                    for (int nt = 0; nt < 2; ++nt)
                        acc[mt][nt] = __builtin_amdgcn_mfma_f32_32x32x16_bf16(bh_[nt], ah[mt], acc[mt][nt], 0, 0, 0);
            }
        }
    }
    #undef LOADT
    #undef WRITET

    #pragma unroll
    for (int mt = 0; mt < 2; ++mt) {
        #pragma unroll
        for (int nt = 0; nt < 2; ++nt) {
            if (z == 2) {
                const int mcol = m0 + wr * 64 + mt * 32 + (lane & 31);
                const int bb = mcol >> 11, tt = mcol & (SEQL - 1);
                #pragma unroll
                for (int r = 0; r < 16; ++r) {
                    int nrow = n0 + wc * 64 + nt * 32 + (r & 3) + 8 * (r >> 2) + 4 * (lane >> 5);
                    int head = nrow >> 6, dd = nrow & 63;
                    Vt[((size_t)(bb * NH + head) * HD + dd) * SEQL + tt] = f2bf(acc[mt][nt][r]);
                }
            } else {
                const int ncol = n0 + wc * 64 + nt * 32 + (lane & 31);
                const int head = ncol >> 6, d = ncol & 63;
                #pragma unroll
                for (int r = 0; r < 16; ++r) {
                    int mrow = m0 + wr * 64 + mt * 32 + (r & 3) + 8 * (r >> 2) + 4 * (lane >> 5);
                    int bb = mrow >> 11, t = mrow & (SEQL - 1);
                    size_t idx = ((size_t)(bb * NH + head) * SEQL + t) * HD + d;
                    float v = acc[mt][nt][r] * oscale;
                    unsigned short hi = f2bf(v);
                    Ohi[idx] = hi;
                    union { unsigned u; float f; } hf; hf.u = ((unsigned)hi) << 16;
                    Olo[idx] = f2bf(v - hf.f);
                }
            }
        }
    }
}

// ---------------------------------------------------------------------------
// Causal flash attention, SPLIT-KV (round-10 version, unchanged).
// ---------------------------------------------------------------------------
__global__ __launch_bounds__(256) void attn_mfma_kernel(
    const unsigned short* __restrict__ Qhi, const unsigned short* __restrict__ Qlo,
    const unsigned short* __restrict__ Khi, const unsigned short* __restrict__ Klo,
    const unsigned short* __restrict__ Vt,
    unsigned short* __restrict__ Op0, unsigned short* __restrict__ Op1,
    float* __restrict__ Ml)
{
    __shared__ unsigned short smem[2][3][4224];   // [buf][Khi,Klo,Vt]

    const int bid  = blockIdx.x;          // 0..1023
    const int xcd  = bid & 7;
    const int idx  = bid >> 3;            // 0..127 within XCD
    const int bh   = xcd * 4 + (idx & 3); // 4 heads per XCD
    const int rest = idx >> 2;            // 0..31
    const int j    = 15 - (rest >> 1);    // heavy qgroups first
    const int sp   = rest & 1;

    const int tid  = threadIdx.x;
    const int wid  = tid >> 6;            // 0..3
    const int lane = tid & 63;
    const int ln   = lane & 31;
    const int h    = lane >> 5;

    const int qb_idx = 4 * j + wid;       // consecutive q-blocks
    const int qb     = qb_idx * 32;
    const int qglob  = qb + ln;
    const int cutoff = 2 * j + (wid >> 1);            // last tile this wave needs
    const int tbeg   = sp ? (j + 1) : 0;
    const int tend   = sp ? (2 * j + 2) : (j + 1);

    const unsigned short* __restrict__ Qbh = Qhi + (size_t)bh * SEQL * HD;
    const unsigned short* __restrict__ Qbl = Qlo + (size_t)bh * SEQL * HD;
    const unsigned short* __restrict__ Kbh = Khi + (size_t)bh * SEQL * HD;
    const unsigned short* __restrict__ Kbl = Klo + (size_t)bh * SEQL * HD;
    const unsigned short* __restrict__ Vtb = Vt  + (size_t)bh * HD * SEQL;

    // Q fragments (B operand), prescaled by QSCALE in the GEMM
    bf16x8 qhi[4], qlo[4];
    #pragma unroll
    for (int c = 0; c < 4; ++c) {
        qhi[c] = *(const bf16x8*)(Qbh + (size_t)qglob * HD + c * 16 + h * 8);
        qlo[c] = *(const bf16x8*)(Qbl + (size_t)qglob * HD + c * 16 + h * 8);
    }

    // staging geometry (2 chunks per thread)
    int s_[2], d8_[2], ks_[2];
    #pragma unroll
    for (int ff = 0; ff < 2; ++ff) {
        int fidx = ff * 256 + tid;
        s_[ff]  = fidx >> 3;
        d8_[ff] = fidx & 7;
        ks_[ff] = slot16((s_[ff] >> 5) * 4 + (d8_[ff] >> 1),
                         (s_[ff] & 31) + 32 * (d8_[ff] & 1)) * 8;
    }

    bf16x8 kh[2], kl[2], vv[2];
    // prologue: load + write tile tbeg; load tile tbeg+1 into regs
    {
        const int s0p = tbeg * 64;
        #pragma unroll
        for (int ff = 0; ff < 2; ++ff) {
            kh[ff] = *(const bf16x8*)(Kbh + (size_t)(s0p + s_[ff]) * HD + d8_[ff] * 8);
            kl[ff] = *(const bf16x8*)(Kbl + (size_t)(s0p + s_[ff]) * HD + d8_[ff] * 8);
            vv[ff] = *(const bf16x8*)(Vtb + (size_t)s_[ff] * SEQL + s0p + d8_[ff] * 8);
        }
        const int pb = tbeg & 1;
        #pragma unroll
        for (int ff = 0; ff < 2; ++ff) {
            *(bf16x8*)(&smem[pb][0][ks_[ff]]) = kh[ff];
            *(bf16x8*)(&smem[pb][1][ks_[ff]]) = kl[ff];
            *(bf16x8*)(&smem[pb][2][ks_[ff]]) = vv[ff];
        }
        if (tbeg + 1 < tend) {
            const int s0n = (tbeg + 1) * 64;
            #pragma unroll
            for (int ff = 0; ff < 2; ++ff) {
                kh[ff] = *(const bf16x8*)(Kbh + (size_t)(s0n + s_[ff]) * HD + d8_[ff] * 8);
                kl[ff] = *(const bf16x8*)(Kbl + (size_t)(s0n + s_[ff]) * HD + d8_[ff] * 8);
                vv[ff] = *(const bf16x8*)(Vtb + (size_t)s_[ff] * SEQL + s0n + d8_[ff] * 8);
            }
        }
    }

    f32x16 oacc[2] = {};
    float m_run = -1e30f, l_run = 0.f;

    for (int t = tbeg; t < tend; ++t) {
        __syncthreads();    // buf[t&1] staged; prev readers of buf[(t+1)&1] done
        if (t + 1 < tend) {
            const int nb = (t + 1) & 1;
            #pragma unroll
            for (int ff = 0; ff < 2; ++ff) {
                *(bf16x8*)(&smem[nb][0][ks_[ff]]) = kh[ff];
                *(bf16x8*)(&smem[nb][1][ks_[ff]]) = kl[ff];
                *(bf16x8*)(&smem[nb][2][ks_[ff]]) = vv[ff];
            }
            if (t + 2 < tend) {
                const int s0n = (t + 2) * 64;
                #pragma unroll
                for (int ff = 0; ff < 2; ++ff) {
                    kh[ff] = *(const bf16x8*)(Kbh + (size_t)(s0n + s_[ff]) * HD + d8_[ff] * 8);
                    kl[ff] = *(const bf16x8*)(Kbl + (size_t)(s0n + s_[ff]) * HD + d8_[ff] * 8);
                    vv[ff] = *(const bf16x8*)(Vtb + (size_t)s_[ff] * SEQL + s0n + d8_[ff] * 8);
                }
            }
        }

        if (t <= cutoff) {
            const int cb = t & 1;
            const int s0 = t * 64;
            const bf16x8* khf = (const bf16x8*)&smem[cb][0][0];
            const bf16x8* klf = (const bf16x8*)&smem[cb][1][0];
            const bf16x8* vtf = (const bf16x8*)&smem[cb][2][0];

            // ---- QK^T (split bf16, 3 MFMA per 16-d chunk) ----
            f32x16 sacc[2] = {};
            __builtin_amdgcn_s_setprio(1);
            #pragma unroll
            for (int sb = 0; sb < 2; ++sb) {
                #pragma unroll
                for (int c = 0; c < 4; ++c) {
                    bf16x8 ah = khf[slot16(sb * 4 + c, lane)];
                    bf16x8 al = klf[slot16(sb * 4 + c, lane)];
                    sacc[sb] = __builtin_amdgcn_mfma_f32_32x32x16_bf16(ah, qhi[c], sacc[sb], 0, 0, 0);
                    sacc[sb] = __builtin_amdgcn_mfma_f32_32x32x16_bf16(ah, qlo[c], sacc[sb], 0, 0, 0);
                    sacc[sb] = __builtin_amdgcn_mfma_f32_32x32x16_bf16(al, qhi[c], sacc[sb], 0, 0, 0);
                }
            }
            __builtin_amdgcn_s_setprio(0);

            // ---- causal mask (wave-uniform branch; last tile(s) only) ----
            if ((s0 + 63) > qb) {
                #pragma unroll
                for (int sb = 0; sb < 2; ++sb)
                    #pragma unroll
                    for (int r = 0; r < 16; ++r) {
                        int srow = (r & 3) + 8 * (r >> 2) + 4 * h + sb * 32;
                        if ((s0 + srow) > qglob) sacc[sb][r] = -1e30f;
                    }
            }

            // ---- online softmax (exp2 domain) ----
            float mtile = -1e30f;
            #pragma unroll
            for (int sb = 0; sb < 2; ++sb)
                #pragma unroll
                for (int r = 0; r < 16; ++r)
                    mtile = fmaxf(mtile, sacc[sb][r]);
            mtile = fmaxf(mtile, __shfl_xor(mtile, 32));

            if (!__all(mtile - m_run <= 11.5f)) {
                const float mnew  = fmaxf(m_run, mtile);
                const float alpha = exp2f(m_run - mnew);
                l_run *= alpha;
                #pragma unroll
                for (int dt = 0; dt < 2; ++dt)
                    #pragma unroll
                    for (int r = 0; r < 16; ++r)
                        oacc[dt][r] *= alpha;
                m_run = mnew;
            }

            float ps0 = 0.f, ps1 = 0.f;
            unsigned pw[2][8];
            #pragma unroll
            for (int sb = 0; sb < 2; ++sb) {
                #pragma unroll
                for (int r2 = 0; r2 < 8; ++r2) {
                    float p0 = exp2f(sacc[sb][2 * r2]     - m_run);
                    float p1 = exp2f(sacc[sb][2 * r2 + 1] - m_run);
                    if (sb == 0) ps0 += p0 + p1; else ps1 += p0 + p1;
                    pw[sb][r2] = cvt_pk_bf16(p0, p1);
                }
            }
            float psum = ps0 + ps1;
            psum += __shfl_xor(psum, 32);
            l_run += psum;

            // ---- P^T B-frags via permlane32_swap ----
            bf16x8 pfrag[4];
            #pragma unroll
            for (int sb = 0; sb < 2; ++sb) {
                #pragma unroll
                for (int c = 0; c < 2; ++c) {
                    unsigned u0 = pw[sb][4 * c + 0], u2 = pw[sb][4 * c + 2];
                    unsigned u1 = pw[sb][4 * c + 1], u3 = pw[sb][4 * c + 3];
                    plane_swap(u0, u2);
                    plane_swap(u1, u3);
                    union { unsigned u[4]; bf16x8 v; } cvt;
                    cvt.u[0] = u0; cvt.u[1] = u1; cvt.u[2] = u2; cvt.u[3] = u3;
                    pfrag[sb * 2 + c] = cvt.v;
                }
            }

            // ---- PV: O^T[d][q] += V^T x P^T ----
            __builtin_amdgcn_s_setprio(1);
            #pragma unroll
            for (int dt = 0; dt < 2; ++dt)
                #pragma unroll
                for (int sc = 0; sc < 4; ++sc)
                    oacc[dt] = __builtin_amdgcn_mfma_f32_32x32x16_bf16(
                        vtf[slot16(dt * 4 + sc, lane)], pfrag[sc], oacc[dt], 0, 0, 0);
            __builtin_amdgcn_s_setprio(0);
        }
    }

    // ---- epilogue: write UNNORMALIZED partial O (bf16, AO layout) + (m,l) ----
    unsigned short* op = (sp ? Op1 : Op0)
        + ((size_t)(bh >> 4) * SEQL + qglob) * NEMB + (bh & 15) * HD;
    #pragma unroll
    for (int dt = 0; dt < 2; ++dt) {
        #pragma unroll
        for (int rg = 0; rg < 4; ++rg) {
            int d0 = dt * 32 + rg * 8 + h * 4;
            uint2 w;
            w.x = cvt_pk_bf16(oacc[dt][rg * 4 + 0], oacc[dt][rg * 4 + 1]);
            w.y = cvt_pk_bf16(oacc[dt][rg * 4 + 2], oacc[dt][rg * 4 + 3]);
            *(uint2*)(op + d0) = w;
        }
    }
    if (h == 0) {
        float2 mlv; mlv.x = m_run; mlv.y = l_run;
        *(float2*)(Ml + ((size_t)(sp * 32 + bh) * SEQL + qglob) * 2) = mlv;
    }
}

// ---------------------------------------------------------------------------
// Split-KV merge: out = (o0*w0 + o1*w1) / (l0*w0 + l1*w1), wi = exp2(mi - M).
// ---------------------------------------------------------------------------
__global__ __launch_bounds__(256) void attn_merge_kernel(
    unsigned short* __restrict__ Op0, const unsigned short* __restrict__ Op1,
    const float* __restrict__ Ml)
{
    const int gid  = blockIdx.x * 256 + threadIdx.x;   // 0 .. 4096*128-1
    const int row  = gid >> 7;                         // 0..4095
    const int col  = (gid & 127) * 8;                  // 0..1016
    const int bh   = ((row >> 11) << 4) + (col >> 6);
    const int q    = row & (SEQL - 1);

    float2 ml0 = *(const float2*)(Ml + ((size_t)bh * SEQL + q) * 2);
    float2 ml1 = *(const float2*)(Ml + ((size_t)(32 + bh) * SEQL + q) * 2);
    const float M  = fmaxf(ml0.x, ml1.x);
    const float w0 = exp2f(ml0.x - M);
    const float w1 = exp2f(ml1.x - M);
    const float rd = 1.0f / (ml0.y * w0 + ml1.y * w1);
    const float f0 = w0 * rd, f1 = w1 * rd;

    size_t off = (size_t)row * NEMB + col;
    uint4 a = *(const uint4*)(Op0 + off);
    uint4 b = *(const uint4*)(Op1 + off);
    const unsigned short* ap = (const unsigned short*)&a;
    const unsigned short* bp = (const unsigned short*)&b;
    uint4 o;
    unsigned* opw = (unsigned*)&o;
    #pragma unroll
    for (int i = 0; i < 4; ++i) {
        float r0 = bf2f(ap[2*i])     * f0 + bf2f(bp[2*i])     * f1;
        float r1 = bf2f(ap[2*i + 1]) * f0 + bf2f(bp[2*i + 1]) * f1;
        opw[i] = cvt_pk_bf16(r0, r1);
    }
    *(uint4*)(Op0 + off) = o;
}

// ---------------------------------------------------------------------------
// Output projection + bias, BM=BN=128 (round-10 version), pipelined.
// ---------------------------------------------------------------------------
__global__ __launch_bounds__(256, 2) void out_proj_kernel(
    const unsigned short* __restrict__ A, const unsigned short* __restrict__ B,
    const float* __restrict__ bias, float* __restrict__ out)
{
    __shared__ unsigned short smem[2][2][4224];

    const int m0 = blockIdx.x * 128;
    const int n0 = blockIdx.y * 128;
    const int tid  = threadIdx.x;
    const int wid  = tid >> 6, lane = tid & 63;
    const int wr   = wid >> 1, wc = wid & 1;

    int roff_[2], slot_[2];
    #pragma unroll
    for (int q = 0; q < 2; ++q) {
        int f   = q * 256 + tid;
        int row = f >> 2;
        int k8  = (f & 3) * 8;
        roff_[q] = row * 1024 + k8;
        slot_[q] = slot16((row >> 5) * 2 + (k8 >> 4), (row & 31) + 32 * ((k8 >> 3) & 1)) * 8;
    }
    const unsigned short* __restrict__ Ab = A + (size_t)m0 * 1024;
    const unsigned short* __restrict__ Bb = B + (size_t)n0 * 1024;

    bf16x8 pa[2], pb[2];
    #pragma unroll
    for (int q = 0; q < 2; ++q) {
        pa[q] = *(const bf16x8*)(Ab + roff_[q]);
        pb[q] = *(const bf16x8*)(Bb + roff_[q]);
    }
    #pragma unroll
    for (int q = 0; q < 2; ++q) {
        *(bf16x8*)(&smem[0][0][slot_[q]]) = pa[q];
        *(bf16x8*)(&smem[0][1][slot_[q]]) = pb[q];
    }
    #pragma unroll
    for (int q = 0; q < 2; ++q) {
        pa[q] = *(const bf16x8*)(Ab + roff_[q] + 32);
        pb[q] = *(const bf16x8*)(Bb + roff_[q] + 32);
    }

    f32x16 acc[2][2] = {};

    for (int t = 0; t < 32; ++t) {
        __syncthreads();
        if (t + 1 < 32) {
            const int nb = (t + 1) & 1;
            #pragma unroll
            for (int q = 0; q < 2; ++q) {
                *(bf16x8*)(&smem[nb][0][slot_[q]]) = pa[q];
                *(bf16x8*)(&smem[nb][1][slot_[q]]) = pb[q];
            }
            if (t + 2 < 32) {
                #pragma unroll
                for (int q = 0; q < 2; ++q) {
                    pa[q] = *(const bf16x8*)(Ab + roff_[q] + (t + 2) * 32);
                    pb[q] = *(const bf16x8*)(Bb + roff_[q] + (t + 2) * 32);
                }
            }
        }
        const int cb = t & 1;
        const unsigned short* a_s = smem[cb][0];
        const unsigned short* b_s = smem[cb][1];
        #pragma unroll
        for (int kch = 0; kch < 2; ++kch) {
            bf16x8 ah[2], bh_[2];
            #pragma unroll
            for (int mt = 0; mt < 2; ++mt)
                ah[mt] = *(const bf16x8*)(a_s + slot16((2 * wr + mt) * 2 + kch, lane) * 8);
            #pragma unroll
            for (int nt = 0; nt < 2; ++nt)
                bh_[nt] = *(const bf16x8*)(b_s + slot16((2 * wc + nt) * 2 + kch, lane) * 8);
            #pragma unroll
            for (int mt = 0; mt < 2; ++mt)
                #pragma unroll
                for (int nt = 0; nt < 2; ++nt)
                    acc[mt][nt] = __builtin_amdgcn_mfma_f32_32x32x16_bf16(ah[mt], bh_[nt], acc[mt][nt], 0, 0, 0);
        }
    }

    #pragma unroll
    for (int mt = 0; mt < 2; ++mt) {
        #pragma unroll
        for (int nt = 0; nt < 2; ++nt) {
            const int ncol = n0 + wc * 64 + nt * 32 + (lane & 31);
            const float bv = bias[ncol];
            #pragma unroll
            for (int r = 0; r < 16; ++r) {
                int mrow = m0 + wr * 64 + mt * 32 + (r & 3) + 8 * (r >> 2) + 4 * (lane >> 5);
                out[(size_t)mrow * 1024 + ncol] = acc[mt][nt][r] + bv;
            }
        }
    }
}

// ---------------------------------------------------------------------------
extern "C" void kernel_launch(void* const* d_in, const int* in_sizes, int n_in,
                              void* d_out, int out_size, void* d_ws, size_t ws_size,
                              hipStream_t stream)
{
    const float* ix = (const float*)d_in[0];
    const float* Wq = (const float*)d_in[1];
    const float* Wk = (const float*)d_in[2];
    const float* Wv = (const float*)d_in[3];
    const float* Wp = (const float*)d_in[4];
    const float* bp = (const float*)d_in[5];
    float* out = (float*)d_out;

    char* ws = (char*)d_ws;
    #define WSOFF(mb) ((unsigned short*)(ws + (size_t)(mb) * 1024 * 1024))
    unsigned short* ix_hi  = WSOFF(0);    // dead after qkv_gemm
    unsigned short* ix_lo  = WSOFF(8);
    unsigned short* Wqt_hi = WSOFF(16);
    unsigned short* Wqt_lo = WSOFF(18);
    unsigned short* Wkt_hi = WSOFF(20);
    unsigned short* Wkt_lo = WSOFF(22);
    unsigned short* Wvt_hi = WSOFF(24);
    unsigned short* Qhi    = WSOFF(26);
    unsigned short* Qlo    = WSOFF(34);
    unsigned short* Khi    = WSOFF(42);
    unsigned short* Klo    = WSOFF(50);
    unsigned short* Wpt    = WSOFF(58);   // peak ws usage: 60 MB
    unsigned short* Op0    = WSOFF(0);    // partial O split 0 (aliases ix_hi)
    unsigned short* Op1    = WSOFF(8);    // partial O split 1 (aliases ix_lo)
    float*          Ml     = (float*)WSOFF(16);  // (m,l) pairs (aliases Wqt)
    unsigned short* Vt     = (unsigned short*)d_out;  // 8 MB scratch inside d_out
    #undef WSOFF

    // 1. split-convert ix
    split_convert_kernel<<<MROWS * NEMB / 4 / 256, 256, 0, stream>>>(ix, ix_hi, ix_lo);
    // 2. transpose+convert all weights
    transpose_convert_kernel<<<dim3(16, 16, 4), 256, 0, stream>>>(
        Wq, Wk, Wv, Wp, Wqt_hi, Wqt_lo, Wkt_hi, Wkt_lo, Wvt_hi, Wpt);
    // 3. fused Q/K/V projections (z-interleaved 1D grid: 768 blocks)
    qkv_gemm<<<768, 256, 0, stream>>>(
        ix_hi, ix_lo, Wqt_hi, Wqt_lo, Wkt_hi, Wkt_lo, Wvt_hi,
        Qhi, Qlo, Khi, Klo, Vt);
    // 4. attention: split-KV partials (1024 blocks), then merge
    attn_mfma_kernel<<<1024, 256, 0, stream>>>(Qhi, Qlo, Khi, Klo, Vt, Op0, Op1, Ml);
    attn_merge_kernel<<<MROWS * NEMB / 8 / 256, 256, 0, stream>>>(Op0, Op1, Ml);
    // 5. output projection + bias
    out_proj_kernel<<<dim3(MROWS / 128, NEMB / 128), 256, 0, stream>>>(Op0, Wpt, bp, out);
}

// Round 13
// 172.957 us; speedup vs baseline: 1.1401x; 1.1401x over previous
//
#include <hip/hip_runtime.h>

#define BATCH 2
#define SEQL  2048
#define NEMB  1024
#define NH    16
#define HD    64
#define MROWS (BATCH*SEQL)   // 4096

// Q prescale: sqrt(C) * log2(e) so scores are in exp2 domain
#define QSCALE 46.166241308446828f

typedef short bf16x8 __attribute__((ext_vector_type(8)));
typedef float f32x16 __attribute__((ext_vector_type(16)));

// round-to-nearest-even float -> bf16 bits
__device__ __forceinline__ unsigned short f2bf(float x) {
    union { float f; unsigned u; } v; v.f = x;
    unsigned r = v.u + 0x7FFFu + ((v.u >> 16) & 1u);
    return (unsigned short)(r >> 16);
}
__device__ __forceinline__ void split_bf16(float x, unsigned short& hi, unsigned short& lo) {
    hi = f2bf(x);
    union { unsigned u; float f; } h; h.u = ((unsigned)hi) << 16;
    lo = f2bf(x - h.f);
}
__device__ __forceinline__ float bf2f(unsigned short b) {
    union { unsigned u; float f; } v; v.u = ((unsigned)b) << 16;
    return v.f;
}
// packed f32x2 -> bf16x2 (hardware cvt, RNE)
__device__ __forceinline__ unsigned cvt_pk_bf16(float a, float b) {
    unsigned r;
    asm("v_cvt_pk_bf16_f32 %0, %1, %2" : "=v"(r) : "v"(a), "v"(b));
    return r;
}
// v_permlane32_swap_b32: a.hi_lanes <-> b.lo_lanes (full-rate VALU lane swap)
__device__ __forceinline__ void plane_swap(unsigned& a, unsigned& b) {
    asm volatile("v_permlane32_swap_b32 %0, %1" : "+v"(a), "+v"(b));
}

// Padded fragment-linear LDS slot (16B units): chunk stride 66, half offset 33.
__device__ __forceinline__ int slot16(int chunk, int lane) {
    return chunk * 66 + (lane & 31) + 33 * (lane >> 5);
}

// ---------------------------------------------------------------------------
// Fused conversion: bid<4096 -> split-convert ix; bid>=4096 -> transpose+
// convert weights (Wq/Wk hi+lo, Wv hi, Wp hi) -> Wt[n][c] (k-fast) bf16.
// ---------------------------------------------------------------------------
__global__ __launch_bounds__(256) void convert_kernel(
    const float* __restrict__ ixsrc,
    const float* __restrict__ Wq, const float* __restrict__ Wk,
    const float* __restrict__ Wv, const float* __restrict__ Wp,
    unsigned short* __restrict__ ixhi, unsigned short* __restrict__ ixlo,
    unsigned short* __restrict__ qhi, unsigned short* __restrict__ qlo,
    unsigned short* __restrict__ khi, unsigned short* __restrict__ klo,
    unsigned short* __restrict__ vhi, unsigned short* __restrict__ pt)
{
    __shared__ float tile[64][68];
    const int bid = blockIdx.x;
    const int tid = threadIdx.x;

    if (bid < 4096) {
        int i = (bid * 256 + tid) * 4;
        float4 v = *(const float4*)(ixsrc + i);
        unsigned short h[4], l[4];
        split_bf16(v.x, h[0], l[0]); split_bf16(v.y, h[1], l[1]);
        split_bf16(v.z, h[2], l[2]); split_bf16(v.w, h[3], l[3]);
        uint2 ph, pl;
        ph.x = h[0] | ((unsigned)h[1] << 16); ph.y = h[2] | ((unsigned)h[3] << 16);
        pl.x = l[0] | ((unsigned)l[1] << 16); pl.y = l[2] | ((unsigned)l[3] << 16);
        *(uint2*)(ixhi + i) = ph;
        *(uint2*)(ixlo + i) = pl;
        return;
    }

    const int t  = bid - 4096;            // 0..1023
    const int z  = t >> 8;                // 0..3
    const int rem = t & 255;
    const int hb = (rem >> 4) & 15;
    const int c0 = (rem & 15) * 64;
    const float* src; int rstride; unsigned short* dhi; unsigned short* dlo;
    if (z == 0)      { src = Wq + (size_t)hb * 65536; rstride = 64;   dhi = qhi; dlo = qlo; }
    else if (z == 1) { src = Wk + (size_t)hb * 65536; rstride = 64;   dhi = khi; dlo = klo; }
    else if (z == 2) { src = Wv + (size_t)hb * 65536; rstride = 64;   dhi = vhi; dlo = nullptr; }
    else             { src = Wp + (size_t)hb * 64;    rstride = 1024; dhi = pt;  dlo = nullptr; }
    #pragma unroll
    for (int i = 0; i < 4; ++i) {
        int fidx = i * 256 + tid;
        int r  = fidx >> 4;
        int dq = (fidx & 15) * 4;
        float4 v = *(const float4*)(src + (size_t)(c0 + r) * rstride + dq);
        *(float4*)&tile[r][dq] = v;
    }
    __syncthreads();
    #pragma unroll
    for (int i = 0; i < 4; ++i) {
        int fidx = i * 256 + tid;
        int d  = fidx >> 4;
        int cq = (fidx & 15) * 4;
        size_t base = (size_t)(hb * 64 + d) * 1024 + c0 + cq;
        unsigned short hh[4], ll[4];
        #pragma unroll
        for (int j = 0; j < 4; ++j) split_bf16(tile[cq + j][d], hh[j], ll[j]);
        uint2 ph; ph.x = hh[0] | ((unsigned)hh[1] << 16); ph.y = hh[2] | ((unsigned)hh[3] << 16);
        *(uint2*)(dhi + base) = ph;
        if (dlo) {
            uint2 pl; pl.x = ll[0] | ((unsigned)ll[1] << 16); pl.y = ll[2] | ((unsigned)ll[3] << 16);
            *(uint2*)(dlo + base) = pl;
        }
    }
}

// ---------------------------------------------------------------------------
// Fused QKV projection GEMM, 1024 blocks, one launch:
//   bid <  512: Q/K split 3-MFMA path, BM=BN=128 (round-10 structure;
//               m-fastest within a fixed B n-panel for L2 B-reuse).
//   bid >= 512: V half-blocks, BM=128 x BN=64, operand-swapped (V^T out).
//               Dispatched LAST -> they backfill the residency tail.
// ---------------------------------------------------------------------------
__global__ __launch_bounds__(256, 2) void qkv_gemm(
    const unsigned short* __restrict__ Ahi, const unsigned short* __restrict__ Alo,
    const unsigned short* __restrict__ Bq_hi, const unsigned short* __restrict__ Bq_lo,
    const unsigned short* __restrict__ Bk_hi, const unsigned short* __restrict__ Bk_lo,
    const unsigned short* __restrict__ Bv_hi,
    unsigned short* __restrict__ Qhi, unsigned short* __restrict__ Qlo,
    unsigned short* __restrict__ Khi, unsigned short* __restrict__ Klo,
    unsigned short* __restrict__ Vt)
{
    __shared__ unsigned short smem[2][4][4224];   // [buf][Ahi,Bhi,Alo,Blo]

    const int bid = blockIdx.x;
    const int tid  = threadIdx.x;
    const int wid  = tid >> 6, lane = tid & 63;
    const int wr   = wid >> 1, wc = wid & 1;

    if (bid < 512) {
        // ---------------- Q/K split path (BM=BN=128) ----------------
        const int z   = bid >> 8;            // 0=Q, 1=K
        const int xy  = bid & 255;
        const int m0  = (xy & 31) * 128;     // m fastest -> shared B-panel
        const int n0  = (xy >> 5) * 128;
        const unsigned short* __restrict__ Bhi = z ? Bk_hi : Bq_hi;
        const unsigned short* __restrict__ Blo = z ? Bk_lo : Bq_lo;
        unsigned short* __restrict__ Ohi = z ? Khi : Qhi;
        unsigned short* __restrict__ Olo = z ? Klo : Qlo;
        const float oscale = z ? 1.0f : QSCALE;

        int roff_[2], slot_[2];
        #pragma unroll
        for (int q = 0; q < 2; ++q) {
            int f   = q * 256 + tid;
            int row = f >> 2;
            int k8  = (f & 3) * 8;
            roff_[q] = row * 1024 + k8;
            slot_[q] = slot16((row >> 5) * 2 + (k8 >> 4), (row & 31) + 32 * ((k8 >> 3) & 1)) * 8;
        }
        const unsigned short* __restrict__ Ah = Ahi + (size_t)m0 * 1024;
        const unsigned short* __restrict__ Bh = Bhi + (size_t)n0 * 1024;
        const unsigned short* __restrict__ Al = Alo + (size_t)m0 * 1024;
        const unsigned short* __restrict__ Bl = Blo + (size_t)n0 * 1024;

        bf16x8 pah[2], pbh[2], pal[2], pbl[2];

        #define LOADT(KK)  do { _Pragma("unroll")                               \
            for (int q = 0; q < 2; ++q) {                                       \
                pah[q] = *(const bf16x8*)(Ah + roff_[q] + (KK));                \
                pbh[q] = *(const bf16x8*)(Bh + roff_[q] + (KK));                \
                pal[q] = *(const bf16x8*)(Al + roff_[q] + (KK));                \
                pbl[q] = *(const bf16x8*)(Bl + roff_[q] + (KK));                \
            } } while (0)

        #define WRITET(NB) do { _Pragma("unroll")                               \
            for (int q = 0; q < 2; ++q) {                                       \
                *(bf16x8*)(&smem[NB][0][slot_[q]]) = pah[q];                    \
                *(bf16x8*)(&smem[NB][1][slot_[q]]) = pbh[q];                    \
                *(bf16x8*)(&smem[NB][2][slot_[q]]) = pal[q];                    \
                *(bf16x8*)(&smem[NB][3][slot_[q]]) = pbl[q];                    \
            } } while (0)

        f32x16 acc[2][2] = {};

        LOADT(0);
        WRITET(0);
        LOADT(32);

        for (int t = 0; t < 32; ++t) {
            __syncthreads();
            if (t + 1 < 32) {
                WRITET((t + 1) & 1);
                if (t + 2 < 32) LOADT((t + 2) * 32);
            }
            const int cb = t & 1;
            const unsigned short* a_hi = smem[cb][0];
            const unsigned short* b_hi = smem[cb][1];
            const unsigned short* a_lo = smem[cb][2];
            const unsigned short* b_lo = smem[cb][3];

            #pragma unroll
            for (int kch = 0; kch < 2; ++kch) {
                bf16x8 ah[2], bh_[2], al[2], bl[2];
                #pragma unroll
                for (int mt = 0; mt < 2; ++mt) {
                    ah[mt] = *(const bf16x8*)(a_hi + slot16((2 * wr + mt) * 2 + kch, lane) * 8);
                    al[mt] = *(const bf16x8*)(a_lo + slot16((2 * wr + mt) * 2 + kch, lane) * 8);
                }
                #pragma unroll
                for (int nt = 0; nt < 2; ++nt) {
                    bh_[nt] = *(const bf16x8*)(b_hi + slot16((2 * wc + nt) * 2 + kch, lane) * 8);
                    bl[nt]  = *(const bf16x8*)(b_lo + slot16((2 * wc + nt) * 2 + kch, lane) * 8);
                }
                #pragma unroll
                for (int mt = 0; mt < 2; ++mt)
                    #pragma unroll
                    for (int nt = 0; nt < 2; ++nt) {
                        acc[mt][nt] = __builtin_amdgcn_mfma_f32_32x32x16_bf16(ah[mt], bh_[nt], acc[mt][nt], 0, 0, 0);
                        acc[mt][nt] = __builtin_amdgcn_mfma_f32_32x32x16_bf16(ah[mt], bl[nt],  acc[mt][nt], 0, 0, 0);
                        acc[mt][nt] = __builtin_amdgcn_mfma_f32_32x32x16_bf16(al[mt], bh_[nt], acc[mt][nt], 0, 0, 0);
                    }
            }
        }
        #undef LOADT
        #undef WRITET

        #pragma unroll
        for (int mt = 0; mt < 2; ++mt) {
            #pragma unroll
            for (int nt = 0; nt < 2; ++nt) {
                const int ncol = n0 + wc * 64 + nt * 32 + (lane & 31);
                const int head = ncol >> 6, d = ncol & 63;
                #pragma unroll
                for (int r = 0; r < 16; ++r) {
                    int mrow = m0 + wr * 64 + mt * 32 + (r & 3) + 8 * (r >> 2) + 4 * (lane >> 5);
                    int bb = mrow >> 11, tt = mrow & (SEQL - 1);
                    size_t idx = ((size_t)(bb * NH + head) * SEQL + tt) * HD + d;
                    float v = acc[mt][nt][r] * oscale;
                    unsigned short hi = f2bf(v);
                    Ohi[idx] = hi;
                    union { unsigned u; float f; } hf; hf.u = ((unsigned)hi) << 16;
                    Olo[idx] = f2bf(v - hf.f);
                }
            }
        }
    } else {
        // ---------------- V half path (BM=128, BN=64, swapped) ----------------
        const int vid = bid - 512;           // 0..511
        const int m0  = (vid >> 4) * 128;    // n fastest within fixed m-tile
        const int n0  = (vid & 15) * 64;

        int roffA_[2], slotA_[2], roffB, slotB;
        #pragma unroll
        for (int q = 0; q < 2; ++q) {
            int f   = q * 256 + tid;
            int row = f >> 2;
            int k8  = (f & 3) * 8;
            roffA_[q] = row * 1024 + k8;
            slotA_[q] = slot16((row >> 5) * 2 + (k8 >> 4), (row & 31) + 32 * ((k8 >> 3) & 1)) * 8;
        }
        {
            int row = tid >> 2;
            int k8  = (tid & 3) * 8;
            roffB  = row * 1024 + k8;
            slotB  = slot16((row >> 5) * 2 + (k8 >> 4), (row & 31) + 32 * ((k8 >> 3) & 1)) * 8;
        }
        const unsigned short* __restrict__ Ah = Ahi + (size_t)m0 * 1024;
        const unsigned short* __restrict__ Bh = Bv_hi + (size_t)n0 * 1024;

        bf16x8 pa[2], pb;
        #pragma unroll
        for (int q = 0; q < 2; ++q) pa[q] = *(const bf16x8*)(Ah + roffA_[q]);
        pb = *(const bf16x8*)(Bh + roffB);
        #pragma unroll
        for (int q = 0; q < 2; ++q) *(bf16x8*)(&smem[0][0][slotA_[q]]) = pa[q];
        *(bf16x8*)(&smem[0][1][slotB]) = pb;
        #pragma unroll
        for (int q = 0; q < 2; ++q) pa[q] = *(const bf16x8*)(Ah + roffA_[q] + 32);
        pb = *(const bf16x8*)(Bh + roffB + 32);

        f32x16 acc[2] = {};

        for (int t = 0; t < 32; ++t) {
            __syncthreads();
            if (t + 1 < 32) {
                const int nb = (t + 1) & 1;
                #pragma unroll
                for (int q = 0; q < 2; ++q) *(bf16x8*)(&smem[nb][0][slotA_[q]]) = pa[q];
                *(bf16x8*)(&smem[nb][1][slotB]) = pb;
                if (t + 2 < 32) {
                    #pragma unroll
                    for (int q = 0; q < 2; ++q) pa[q] = *(const bf16x8*)(Ah + roffA_[q] + (t + 2) * 32);
                    pb = *(const bf16x8*)(Bh + roffB + (t + 2) * 32);
                }
            }
            const int cb = t & 1;
            const unsigned short* a_s = smem[cb][0];
            const unsigned short* b_s = smem[cb][1];
            #pragma unroll
            for (int kch = 0; kch < 2; ++kch) {
                bf16x8 ah[2], bh_;
                #pragma unroll
                for (int mt = 0; mt < 2; ++mt)
                    ah[mt] = *(const bf16x8*)(a_s + slot16((2 * wr + mt) * 2 + kch, lane) * 8);
                bh_ = *(const bf16x8*)(b_s + slot16(wc * 2 + kch, lane) * 8);
                #pragma unroll
                for (int mt = 0; mt < 2; ++mt)
                    acc[mt] = __builtin_amdgcn_mfma_f32_32x32x16_bf16(bh_, ah[mt], acc[mt], 0, 0, 0);
            }
        }

        // epilogue: acc rows = n-space (d), cols = m-space (t) -> coalesced Vt
        #pragma unroll
        for (int mt = 0; mt < 2; ++mt) {
            const int mcol = m0 + wr * 64 + mt * 32 + (lane & 31);
            const int bb = mcol >> 11, tt = mcol & (SEQL - 1);
            #pragma unroll
            for (int r = 0; r < 16; ++r) {
                int nrow = n0 + wc * 32 + (r & 3) + 8 * (r >> 2) + 4 * (lane >> 5);
                int head = nrow >> 6, dd = nrow & 63;
                Vt[((size_t)(bb * NH + head) * HD + dd) * SEQL + tt] = f2bf(acc[mt][r]);
            }
        }
    }
}

// ---------------------------------------------------------------------------
// Causal flash attention, SPLIT-KV (round-10 version, unchanged).
// ---------------------------------------------------------------------------
__global__ __launch_bounds__(256) void attn_mfma_kernel(
    const unsigned short* __restrict__ Qhi, const unsigned short* __restrict__ Qlo,
    const unsigned short* __restrict__ Khi, const unsigned short* __restrict__ Klo,
    const unsigned short* __restrict__ Vt,
    unsigned short* __restrict__ Op0, unsigned short* __restrict__ Op1,
    float* __restrict__ Ml)
{
    __shared__ unsigned short smem[2][3][4224];   // [buf][Khi,Klo,Vt]

    const int bid  = blockIdx.x;          // 0..1023
    const int xcd  = bid & 7;
    const int idx  = bid >> 3;            // 0..127 within XCD
    const int bh   = xcd * 4 + (idx & 3); // 4 heads per XCD
    const int rest = idx >> 2;            // 0..31
    const int j    = 15 - (rest >> 1);    // heavy qgroups first
    const int sp   = rest & 1;

    const int tid  = threadIdx.x;
    const int wid  = tid >> 6;            // 0..3
    const int lane = tid & 63;
    const int ln   = lane & 31;
    const int h    = lane >> 5;

    const int qb_idx = 4 * j + wid;       // consecutive q-blocks
    const int qb     = qb_idx * 32;
    const int qglob  = qb + ln;
    const int cutoff = 2 * j + (wid >> 1);            // last tile this wave needs
    const int tbeg   = sp ? (j + 1) : 0;
    const int tend   = sp ? (2 * j + 2) : (j + 1);

    const unsigned short* __restrict__ Qbh = Qhi + (size_t)bh * SEQL * HD;
    const unsigned short* __restrict__ Qbl = Qlo + (size_t)bh * SEQL * HD;
    const unsigned short* __restrict__ Kbh = Khi + (size_t)bh * SEQL * HD;
    const unsigned short* __restrict__ Kbl = Klo + (size_t)bh * SEQL * HD;
    const unsigned short* __restrict__ Vtb = Vt  + (size_t)bh * HD * SEQL;

    // Q fragments (B operand), prescaled by QSCALE in the GEMM
    bf16x8 qhi[4], qlo[4];
    #pragma unroll
    for (int c = 0; c < 4; ++c) {
        qhi[c] = *(const bf16x8*)(Qbh + (size_t)qglob * HD + c * 16 + h * 8);
        qlo[c] = *(const bf16x8*)(Qbl + (size_t)qglob * HD + c * 16 + h * 8);
    }

    // staging geometry (2 chunks per thread)
    int s_[2], d8_[2], ks_[2];
    #pragma unroll
    for (int ff = 0; ff < 2; ++ff) {
        int fidx = ff * 256 + tid;
        s_[ff]  = fidx >> 3;
        d8_[ff] = fidx & 7;
        ks_[ff] = slot16((s_[ff] >> 5) * 4 + (d8_[ff] >> 1),
                         (s_[ff] & 31) + 32 * (d8_[ff] & 1)) * 8;
    }

    bf16x8 kh[2], kl[2], vv[2];
    // prologue: load + write tile tbeg; load tile tbeg+1 into regs
    {
        const int s0p = tbeg * 64;
        #pragma unroll
        for (int ff = 0; ff < 2; ++ff) {
            kh[ff] = *(const bf16x8*)(Kbh + (size_t)(s0p + s_[ff]) * HD + d8_[ff] * 8);
            kl[ff] = *(const bf16x8*)(Kbl + (size_t)(s0p + s_[ff]) * HD + d8_[ff] * 8);
            vv[ff] = *(const bf16x8*)(Vtb + (size_t)s_[ff] * SEQL + s0p + d8_[ff] * 8);
        }
        const int pb = tbeg & 1;
        #pragma unroll
        for (int ff = 0; ff < 2; ++ff) {
            *(bf16x8*)(&smem[pb][0][ks_[ff]]) = kh[ff];
            *(bf16x8*)(&smem[pb][1][ks_[ff]]) = kl[ff];
            *(bf16x8*)(&smem[pb][2][ks_[ff]]) = vv[ff];
        }
        if (tbeg + 1 < tend) {
            const int s0n = (tbeg + 1) * 64;
            #pragma unroll
            for (int ff = 0; ff < 2; ++ff) {
                kh[ff] = *(const bf16x8*)(Kbh + (size_t)(s0n + s_[ff]) * HD + d8_[ff] * 8);
                kl[ff] = *(const bf16x8*)(Kbl + (size_t)(s0n + s_[ff]) * HD + d8_[ff] * 8);
                vv[ff] = *(const bf16x8*)(Vtb + (size_t)s_[ff] * SEQL + s0n + d8_[ff] * 8);
            }
        }
    }

    f32x16 oacc[2] = {};
    float m_run = -1e30f, l_run = 0.f;

    for (int t = tbeg; t < tend; ++t) {
        __syncthreads();    // buf[t&1] staged; prev readers of buf[(t+1)&1] done
        if (t + 1 < tend) {
            const int nb = (t + 1) & 1;
            #pragma unroll
            for (int ff = 0; ff < 2; ++ff) {
                *(bf16x8*)(&smem[nb][0][ks_[ff]]) = kh[ff];
                *(bf16x8*)(&smem[nb][1][ks_[ff]]) = kl[ff];
                *(bf16x8*)(&smem[nb][2][ks_[ff]]) = vv[ff];
            }
            if (t + 2 < tend) {
                const int s0n = (t + 2) * 64;
                #pragma unroll
                for (int ff = 0; ff < 2; ++ff) {
                    kh[ff] = *(const bf16x8*)(Kbh + (size_t)(s0n + s_[ff]) * HD + d8_[ff] * 8);
                    kl[ff] = *(const bf16x8*)(Kbl + (size_t)(s0n + s_[ff]) * HD + d8_[ff] * 8);
                    vv[ff] = *(const bf16x8*)(Vtb + (size_t)s_[ff] * SEQL + s0n + d8_[ff] * 8);
                }
            }
        }

        if (t <= cutoff) {
            const int cb = t & 1;
            const int s0 = t * 64;
            const bf16x8* khf = (const bf16x8*)&smem[cb][0][0];
            const bf16x8* klf = (const bf16x8*)&smem[cb][1][0];
            const bf16x8* vtf = (const bf16x8*)&smem[cb][2][0];

            // ---- QK^T (split bf16, 3 MFMA per 16-d chunk) ----
            f32x16 sacc[2] = {};
            __builtin_amdgcn_s_setprio(1);
            #pragma unroll
            for (int sb = 0; sb < 2; ++sb) {
                #pragma unroll
                for (int c = 0; c < 4; ++c) {
                    bf16x8 ah = khf[slot16(sb * 4 + c, lane)];
                    bf16x8 al = klf[slot16(sb * 4 + c, lane)];
                    sacc[sb] = __builtin_amdgcn_mfma_f32_32x32x16_bf16(ah, qhi[c], sacc[sb], 0, 0, 0);
                    sacc[sb] = __builtin_amdgcn_mfma_f32_32x32x16_bf16(ah, qlo[c], sacc[sb], 0, 0, 0);
                    sacc[sb] = __builtin_amdgcn_mfma_f32_32x32x16_bf16(al, qhi[c], sacc[sb], 0, 0, 0);
                }
            }
            __builtin_amdgcn_s_setprio(0);

            // ---- causal mask (wave-uniform branch; last tile(s) only) ----
            if ((s0 + 63) > qb) {
                #pragma unroll
                for (int sb = 0; sb < 2; ++sb)
                    #pragma unroll
                    for (int r = 0; r < 16; ++r) {
                        int srow = (r & 3) + 8 * (r >> 2) + 4 * h + sb * 32;
                        if ((s0 + srow) > qglob) sacc[sb][r] = -1e30f;
                    }
            }

            // ---- online softmax (exp2 domain) ----
            float mtile = -1e30f;
            #pragma unroll
            for (int sb = 0; sb < 2; ++sb)
                #pragma unroll
                for (int r = 0; r < 16; ++r)
                    mtile = fmaxf(mtile, sacc[sb][r]);
            mtile = fmaxf(mtile, __shfl_xor(mtile, 32));

            if (!__all(mtile - m_run <= 11.5f)) {
                const float mnew  = fmaxf(m_run, mtile);
                const float alpha = exp2f(m_run - mnew);
                l_run *= alpha;
                #pragma unroll
                for (int dt = 0; dt < 2; ++dt)
                    #pragma unroll
                    for (int r = 0; r < 16; ++r)
                        oacc[dt][r] *= alpha;
                m_run = mnew;
            }

            float ps0 = 0.f, ps1 = 0.f;
            unsigned pw[2][8];
            #pragma unroll
            for (int sb = 0; sb < 2; ++sb) {
                #pragma unroll
                for (int r2 = 0; r2 < 8; ++r2) {
                    float p0 = exp2f(sacc[sb][2 * r2]     - m_run);
                    float p1 = exp2f(sacc[sb][2 * r2 + 1] - m_run);
                    if (sb == 0) ps0 += p0 + p1; else ps1 += p0 + p1;
                    pw[sb][r2] = cvt_pk_bf16(p0, p1);
                }
            }
            float psum = ps0 + ps1;
            psum += __shfl_xor(psum, 32);
            l_run += psum;

            // ---- P^T B-frags via permlane32_swap ----
            bf16x8 pfrag[4];
            #pragma unroll
            for (int sb = 0; sb < 2; ++sb) {
                #pragma unroll
                for (int c = 0; c < 2; ++c) {
                    unsigned u0 = pw[sb][4 * c + 0], u2 = pw[sb][4 * c + 2];
                    unsigned u1 = pw[sb][4 * c + 1], u3 = pw[sb][4 * c + 3];
                    plane_swap(u0, u2);
                    plane_swap(u1, u3);
                    union { unsigned u[4]; bf16x8 v; } cvt;
                    cvt.u[0] = u0; cvt.u[1] = u1; cvt.u[2] = u2; cvt.u[3] = u3;
                    pfrag[sb * 2 + c] = cvt.v;
                }
            }

            // ---- PV: O^T[d][q] += V^T x P^T ----
            __builtin_amdgcn_s_setprio(1);
            #pragma unroll
            for (int dt = 0; dt < 2; ++dt)
                #pragma unroll
                for (int sc = 0; sc < 4; ++sc)
                    oacc[dt] = __builtin_amdgcn_mfma_f32_32x32x16_bf16(
                        vtf[slot16(dt * 4 + sc, lane)], pfrag[sc], oacc[dt], 0, 0, 0);
            __builtin_amdgcn_s_setprio(0);
        }
    }

    // ---- epilogue: write UNNORMALIZED partial O (bf16, AO layout) + (m,l) ----
    unsigned short* op = (sp ? Op1 : Op0)
        + ((size_t)(bh >> 4) * SEQL + qglob) * NEMB + (bh & 15) * HD;
    #pragma unroll
    for (int dt = 0; dt < 2; ++dt) {
        #pragma unroll
        for (int rg = 0; rg < 4; ++rg) {
            int d0 = dt * 32 + rg * 8 + h * 4;
            uint2 w;
            w.x = cvt_pk_bf16(oacc[dt][rg * 4 + 0], oacc[dt][rg * 4 + 1]);
            w.y = cvt_pk_bf16(oacc[dt][rg * 4 + 2], oacc[dt][rg * 4 + 3]);
            *(uint2*)(op + d0) = w;
        }
    }
    if (h == 0) {
        float2 mlv; mlv.x = m_run; mlv.y = l_run;
        *(float2*)(Ml + ((size_t)(sp * 32 + bh) * SEQL + qglob) * 2) = mlv;
    }
}

// ---------------------------------------------------------------------------
// Split-KV merge: out = (o0*w0 + o1*w1) / (l0*w0 + l1*w1), wi = exp2(mi - M).
// ---------------------------------------------------------------------------
__global__ __launch_bounds__(256) void attn_merge_kernel(
    unsigned short* __restrict__ Op0, const unsigned short* __restrict__ Op1,
    const float* __restrict__ Ml)
{
    const int gid  = blockIdx.x * 256 + threadIdx.x;   // 0 .. 4096*128-1
    const int row  = gid >> 7;                         // 0..4095
    const int col  = (gid & 127) * 8;                  // 0..1016
    const int bh   = ((row >> 11) << 4) + (col >> 6);
    const int q    = row & (SEQL - 1);

    float2 ml0 = *(const float2*)(Ml + ((size_t)bh * SEQL + q) * 2);
    float2 ml1 = *(const float2*)(Ml + ((size_t)(32 + bh) * SEQL + q) * 2);
    const float M  = fmaxf(ml0.x, ml1.x);
    const float w0 = exp2f(ml0.x - M);
    const float w1 = exp2f(ml1.x - M);
    const float rd = 1.0f / (ml0.y * w0 + ml1.y * w1);
    const float f0 = w0 * rd, f1 = w1 * rd;

    size_t off = (size_t)row * NEMB + col;
    uint4 a = *(const uint4*)(Op0 + off);
    uint4 b = *(const uint4*)(Op1 + off);
    const unsigned short* ap = (const unsigned short*)&a;
    const unsigned short* bp = (const unsigned short*)&b;
    uint4 o;
    unsigned* opw = (unsigned*)&o;
    #pragma unroll
    for (int i = 0; i < 4; ++i) {
        float r0 = bf2f(ap[2*i])     * f0 + bf2f(bp[2*i])     * f1;
        float r1 = bf2f(ap[2*i + 1]) * f0 + bf2f(bp[2*i + 1]) * f1;
        opw[i] = cvt_pk_bf16(r0, r1);
    }
    *(uint4*)(Op0 + off) = o;
}

// ---------------------------------------------------------------------------
// Output projection + bias, BM=BN=128 (round-10 version), pipelined.
// ---------------------------------------------------------------------------
__global__ __launch_bounds__(256, 2) void out_proj_kernel(
    const unsigned short* __restrict__ A, const unsigned short* __restrict__ B,
    const float* __restrict__ bias, float* __restrict__ out)
{
    __shared__ unsigned short smem[2][2][4224];

    const int m0 = blockIdx.x * 128;
    const int n0 = blockIdx.y * 128;
    const int tid  = threadIdx.x;
    const int wid  = tid >> 6, lane = tid & 63;
    const int wr   = wid >> 1, wc = wid & 1;

    int roff_[2], slot_[2];
    #pragma unroll
    for (int q = 0; q < 2; ++q) {
        int f   = q * 256 + tid;
        int row = f >> 2;
        int k8  = (f & 3) * 8;
        roff_[q] = row * 1024 + k8;
        slot_[q] = slot16((row >> 5) * 2 + (k8 >> 4), (row & 31) + 32 * ((k8 >> 3) & 1)) * 8;
    }
    const unsigned short* __restrict__ Ab = A + (size_t)m0 * 1024;
    const unsigned short* __restrict__ Bb = B + (size_t)n0 * 1024;

    bf16x8 pa[2], pb[2];
    #pragma unroll
    for (int q = 0; q < 2; ++q) {
        pa[q] = *(const bf16x8*)(Ab + roff_[q]);
        pb[q] = *(const bf16x8*)(Bb + roff_[q]);
    }
    #pragma unroll
    for (int q = 0; q < 2; ++q) {
        *(bf16x8*)(&smem[0][0][slot_[q]]) = pa[q];
        *(bf16x8*)(&smem[0][1][slot_[q]]) = pb[q];
    }
    #pragma unroll
    for (int q = 0; q < 2; ++q) {
        pa[q] = *(const bf16x8*)(Ab + roff_[q] + 32);
        pb[q] = *(const bf16x8*)(Bb + roff_[q] + 32);
    }

    f32x16 acc[2][2] = {};

    for (int t = 0; t < 32; ++t) {
        __syncthreads();
        if (t + 1 < 32) {
            const int nb = (t + 1) & 1;
            #pragma unroll
            for (int q = 0; q < 2; ++q) {
                *(bf16x8*)(&smem[nb][0][slot_[q]]) = pa[q];
                *(bf16x8*)(&smem[nb][1][slot_[q]]) = pb[q];
            }
            if (t + 2 < 32) {
                #pragma unroll
                for (int q = 0; q < 2; ++q) {
                    pa[q] = *(const bf16x8*)(Ab + roff_[q] + (t + 2) * 32);
                    pb[q] = *(const bf16x8*)(Bb + roff_[q] + (t + 2) * 32);
                }
            }
        }
        const int cb = t & 1;
        const unsigned short* a_s = smem[cb][0];
        const unsigned short* b_s = smem[cb][1];
        #pragma unroll
        for (int kch = 0; kch < 2; ++kch) {
            bf16x8 ah[2], bh_[2];
            #pragma unroll
            for (int mt = 0; mt < 2; ++mt)
                ah[mt] = *(const bf16x8*)(a_s + slot16((2 * wr + mt) * 2 + kch, lane) * 8);
            #pragma unroll
            for (int nt = 0; nt < 2; ++nt)
                bh_[nt] = *(const bf16x8*)(b_s + slot16((2 * wc + nt) * 2 + kch, lane) * 8);
            #pragma unroll
            for (int mt = 0; mt < 2; ++mt)
                #pragma unroll
                for (int nt = 0; nt < 2; ++nt)
                    acc[mt][nt] = __builtin_amdgcn_mfma_f32_32x32x16_bf16(ah[mt], bh_[nt], acc[mt][nt], 0, 0, 0);
        }
    }

    #pragma unroll
    for (int mt = 0; mt < 2; ++mt) {
        #pragma unroll
        for (int nt = 0; nt < 2; ++nt) {
            const int ncol = n0 + wc * 64 + nt * 32 + (lane & 31);
            const float bv = bias[ncol];
            #pragma unroll
            for (int r = 0; r < 16; ++r) {
                int mrow = m0 + wr * 64 + mt * 32 + (r & 3) + 8 * (r >> 2) + 4 * (lane >> 5);
                out[(size_t)mrow * 1024 + ncol] = acc[mt][nt][r] + bv;
            }
        }
    }
}

// ---------------------------------------------------------------------------
extern "C" void kernel_launch(void* const* d_in, const int* in_sizes, int n_in,
                              void* d_out, int out_size, void* d_ws, size_t ws_size,
                              hipStream_t stream)
{
    const float* ix = (const float*)d_in[0];
    const float* Wq = (const float*)d_in[1];
    const float* Wk = (const float*)d_in[2];
    const float* Wv = (const float*)d_in[3];
    const float* Wp = (const float*)d_in[4];
    const float* bp = (const float*)d_in[5];
    float* out = (float*)d_out;

    char* ws = (char*)d_ws;
    #define WSOFF(mb) ((unsigned short*)(ws + (size_t)(mb) * 1024 * 1024))
    unsigned short* ix_hi  = WSOFF(0);    // dead after qkv_gemm
    unsigned short* ix_lo  = WSOFF(8);
    unsigned short* Wqt_hi = WSOFF(16);
    unsigned short* Wqt_lo = WSOFF(18);
    unsigned short* Wkt_hi = WSOFF(20);
    unsigned short* Wkt_lo = WSOFF(22);
    unsigned short* Wvt_hi = WSOFF(24);
    unsigned short* Qhi    = WSOFF(26);
    unsigned short* Qlo    = WSOFF(34);
    unsigned short* Khi    = WSOFF(42);
    unsigned short* Klo    = WSOFF(50);
    unsigned short* Wpt    = WSOFF(58);   // peak ws usage: 60 MB
    unsigned short* Op0    = WSOFF(0);    // partial O split 0 (aliases ix_hi)
    unsigned short* Op1    = WSOFF(8);    // partial O split 1 (aliases ix_lo)
    float*          Ml     = (float*)WSOFF(16);  // (m,l) pairs (aliases Wqt)
    unsigned short* Vt     = (unsigned short*)d_out;  // 8 MB scratch inside d_out
    #undef WSOFF

    // 1. fused conversions (ix split + all weight transposes), one launch
    convert_kernel<<<5120, 256, 0, stream>>>(
        ix, Wq, Wk, Wv, Wp, ix_hi, ix_lo,
        Wqt_hi, Wqt_lo, Wkt_hi, Wkt_lo, Wvt_hi, Wpt);
    // 2. fused Q/K/V projections: 512 Q/K blocks then 512 V-half backfill
    qkv_gemm<<<1024, 256, 0, stream>>>(
        ix_hi, ix_lo, Wqt_hi, Wqt_lo, Wkt_hi, Wkt_lo, Wvt_hi,
        Qhi, Qlo, Khi, Klo, Vt);
    // 3. attention: split-KV partials (1024 blocks), then merge
    attn_mfma_kernel<<<1024, 256, 0, stream>>>(Qhi, Qlo, Khi, Klo, Vt, Op0, Op1, Ml);
    attn_merge_kernel<<<MROWS * NEMB / 8 / 256, 256, 0, stream>>>(Op0, Op1, Ml);
    // 4. output projection + bias
    out_proj_kernel<<<dim3(MROWS / 128, NEMB / 128), 256, 0, stream>>>(Op0, Wpt, bp, out);
}